// Round 5
// baseline (3616.609 us; speedup 1.0000x reference)
//
#include <hip/hip_runtime.h>

#define NEG_SLOPE 0.01f
#define GN_EPS 1e-5f

typedef __attribute__((ext_vector_type(8))) __bf16 bf16x8;
typedef __attribute__((ext_vector_type(4))) __bf16 bf16x4;
typedef __attribute__((ext_vector_type(4))) float f32x4;

#define LROW 68   // LDS accumulator row stride (floats): 16B-aligned, bank-spread

// ===========================================================================
// Binned CSR build: bins keyed by (output_tile, k). Histogram -> scan ->
// scatter of packed entries (local_row<<26)|in_idx.
// ===========================================================================
__global__ __launch_bounds__(256) void hist_binned_kernel(
    const int* __restrict__ om, int* __restrict__ cnt, int M, int TK, int BPK)
{
    int k = blockIdx.x / BPK, blk = blockIdx.x % BPK;
    const int* omk = om + (size_t)k * M;
    for (int m = blk * 256 + threadIdx.x; m < M; m += BPK * 256)
        atomicAdd(&cnt[(omk[m] >> 6) * TK + k], 1);
}

__global__ __launch_bounds__(256) void scatter_binned_kernel(
    const int* __restrict__ om, const int* __restrict__ im,
    const int* __restrict__ base, int* __restrict__ cur,
    int* __restrict__ pk, int M, int TK, int BPK)
{
    int k = blockIdx.x / BPK, blk = blockIdx.x % BPK;
    const int* omk = om + (size_t)k * M;
    const int* imk = im + (size_t)k * M;
    for (int m = blk * 256 + threadIdx.x; m < M; m += BPK * 256) {
        int o = omk[m];
        int bin = (o >> 6) * TK + k;
        int p = base[bin] + atomicAdd(&cur[bin], 1);
        pk[p] = ((o & 63) << 26) | imk[m];
    }
}

__global__ __launch_bounds__(256) void scan1_kernel(
    const int* __restrict__ cnt, int* __restrict__ part, int N)
{
    __shared__ int ls[256];
    int b = blockIdx.x, t = threadIdx.x;
    int i0 = b * 1024 + t * 4, s = 0;
#pragma unroll
    for (int u = 0; u < 4; ++u) if (i0 + u < N) s += cnt[i0 + u];
    ls[t] = s; __syncthreads();
    for (int off = 128; off > 0; off >>= 1) {
        if (t < off) ls[t] += ls[t + off];
        __syncthreads();
    }
    if (t == 0) part[b] = ls[0];
}

__global__ void scan2_kernel(int* __restrict__ part, int nb)
{
    if (blockIdx.x == 0 && threadIdx.x == 0) {
        int run = 0;
        for (int i = 0; i < nb; ++i) { int v = part[i]; part[i] = run; run += v; }
    }
}

__global__ __launch_bounds__(256) void scan3_kernel(
    const int* __restrict__ cnt, const int* __restrict__ part,
    int* __restrict__ base, int N)
{
    __shared__ int ls[256];
    int b = blockIdx.x, t = threadIdx.x;
    int i0 = b * 1024 + t * 4;
    int v0 = 0, v1 = 0, v2 = 0, v3 = 0;
    if (i0 + 0 < N) v0 = cnt[i0 + 0];
    if (i0 + 1 < N) v1 = cnt[i0 + 1];
    if (i0 + 2 < N) v2 = cnt[i0 + 2];
    if (i0 + 3 < N) v3 = cnt[i0 + 3];
    int s = v0 + v1 + v2 + v3;
    ls[t] = s; __syncthreads();
    for (int off = 1; off < 256; off <<= 1) {
        int x = (t >= off) ? ls[t - off] : 0;
        __syncthreads();
        ls[t] += x;
        __syncthreads();
    }
    int run = part[b] + ls[t] - s;   // exclusive prefix
    if (i0 + 0 < N) { base[i0 + 0] = run; run += v0; if (i0 + 0 == N - 1) base[N] = run; }
    if (i0 + 1 < N) { base[i0 + 1] = run; run += v1; if (i0 + 1 == N - 1) base[N] = run; }
    if (i0 + 2 < N) { base[i0 + 2] = run; run += v2; if (i0 + 2 == N - 1) base[N] = run; }
    if (i0 + 3 < N) { base[i0 + 3] = run; run += v3; if (i0 + 3 == N - 1) base[N] = run; }
}

// ===========================================================================
// W -> bf16 MFMA fragment layout: Wf[((k*2+h)*4+nt)*64+lane][j] =
//   W[k][(h*32+(lane>>4)*8+j)][nt*16+(lane&15)]
// ===========================================================================
__global__ __launch_bounds__(256) void wfrag_kernel(
    const float* __restrict__ W, __bf16* __restrict__ Wf, int K)
{
    int id = blockIdx.x * 256 + threadIdx.x;
    if (id >= K * 512) return;
    int lane = id & 63, nt = (id >> 6) & 3, h = (id >> 8) & 1, k = id >> 9;
    const float* Wk = W + (size_t)k * 4096;
    __bf16* dst = Wf + (size_t)id * 8;
    int l15 = lane & 15, lg = lane >> 4;
#pragma unroll
    for (int j = 0; j < 8; ++j)
        dst[j] = (__bf16)Wk[(h * 32 + lg * 8 + j) * 64 + nt * 16 + l15];
}

// ===========================================================================
// Fused implicit-GEMM spconv: one block per 64-row output tile. LDS fp32
// accumulator; per-(tile,k) bins -> 16-edge chunks -> 8 MFMAs -> LDS
// scatter-add via NATIVE ds_add_f32 (unsafeAtomicAdd; plain atomicAdd on
// fp32 LDS lowers to a CAS retry loop = the round-4 3608us pathology).
// Write-out fuses GroupNorm stats (sum/sumsq per group).
// A (16x16x32): lane holds A[m=l&15][c=(l>>4)*8+j]; D: row=(l>>4)*4+r, col=l&15.
// ===========================================================================
template<int F32IN>
__global__ __launch_bounds__(256) void conv_fused_kernel(
    const void* __restrict__ feats, const __bf16* __restrict__ Wf,
    const int* __restrict__ base, const int* __restrict__ pk,
    float* __restrict__ acc, float* __restrict__ stats, int N, int TK)
{
    __shared__ float lacc[64 * LROW];
    const int tile = blockIdx.x;
    const int tid  = threadIdx.x;
    const int lane = tid & 63, wv = tid >> 6;
    const int l15  = lane & 15, lg = lane >> 4;

    for (int i = tid; i < 64 * LROW; i += 256) lacc[i] = 0.f;
    __syncthreads();

    const int* bb = base + (size_t)tile * TK;
    const bf16x8* WfV = (const bf16x8*)Wf;

    for (int k = wv; k < TK; k += 4) {
        const int s = bb[k], e = bb[k + 1];
        if (s >= e) continue;
        bf16x8 b[4][2];
#pragma unroll
        for (int nt = 0; nt < 4; ++nt)
#pragma unroll
            for (int h = 0; h < 2; ++h)
                b[nt][h] = WfV[((k * 2 + h) * 4 + nt) * 64 + lane];

        for (int cb = s; cb < e; cb += 16) {
            const int idx = cb + l15;
            const int pkv = pk[idx];              // padded array; tail garbage ok
            const int ii  = pkv & 0x03ffffff;
            bf16x8 a0, a1;
#pragma unroll
            for (int j = 0; j < 8; ++j) { a0[j] = (__bf16)0.f; a1[j] = (__bf16)0.f; }
            if (idx < e) {
                if (F32IN) {
                    const float4* rp = (const float4*)((const float*)feats + (size_t)ii * 64 + lg * 8);
                    float4 u0 = rp[0], u1 = rp[1];
                    float4 u2 = rp[8], u3 = rp[9];   // +32 channels
                    a0[0]=(__bf16)u0.x; a0[1]=(__bf16)u0.y; a0[2]=(__bf16)u0.z; a0[3]=(__bf16)u0.w;
                    a0[4]=(__bf16)u1.x; a0[5]=(__bf16)u1.y; a0[6]=(__bf16)u1.z; a0[7]=(__bf16)u1.w;
                    a1[0]=(__bf16)u2.x; a1[1]=(__bf16)u2.y; a1[2]=(__bf16)u2.z; a1[3]=(__bf16)u2.w;
                    a1[4]=(__bf16)u3.x; a1[5]=(__bf16)u3.y; a1[6]=(__bf16)u3.z; a1[7]=(__bf16)u3.w;
                } else {
                    const bf16x8* rp = (const bf16x8*)((const __bf16*)feats + (size_t)ii * 64 + lg * 8);
                    a0 = rp[0];
                    a1 = rp[4];   // +32 channels
                }
            }
            f32x4 c0 = {0.f,0.f,0.f,0.f}, c1 = c0, c2 = c0, c3 = c0;
            c0 = __builtin_amdgcn_mfma_f32_16x16x32_bf16(a0, b[0][0], c0, 0, 0, 0);
            c1 = __builtin_amdgcn_mfma_f32_16x16x32_bf16(a0, b[1][0], c1, 0, 0, 0);
            c2 = __builtin_amdgcn_mfma_f32_16x16x32_bf16(a0, b[2][0], c2, 0, 0, 0);
            c3 = __builtin_amdgcn_mfma_f32_16x16x32_bf16(a0, b[3][0], c3, 0, 0, 0);
            c0 = __builtin_amdgcn_mfma_f32_16x16x32_bf16(a1, b[0][1], c0, 0, 0, 0);
            c1 = __builtin_amdgcn_mfma_f32_16x16x32_bf16(a1, b[1][1], c1, 0, 0, 0);
            c2 = __builtin_amdgcn_mfma_f32_16x16x32_bf16(a1, b[2][1], c2, 0, 0, 0);
            c3 = __builtin_amdgcn_mfma_f32_16x16x32_bf16(a1, b[3][1], c3, 0, 0, 0);

            f32x4 cc[4] = {c0, c1, c2, c3};
#pragma unroll
            for (int r = 0; r < 4; ++r) {
                int prow = __shfl(pkv, lg * 4 + r);
                int lo   = ((unsigned)prow) >> 26;
                if (cb + lg * 4 + r < e) {
                    float* dst = &lacc[lo * LROW + l15];
#pragma unroll
                    for (int nt = 0; nt < 4; ++nt)
                        unsafeAtomicAdd(dst + nt * 16, cc[nt][r]);   // ds_add_f32
                }
            }
        }
    }
    __syncthreads();

    // ---- write-out + fused GN stats ----
    const int row = tid >> 2;
    const int c0  = (tid & 3) * 16;
    const int o   = tile * 64 + row;
    float s0 = 0.f, q0 = 0.f, s1 = 0.f, q1 = 0.f;
    if (o < N) {
        float4* dst = (float4*)(acc + (size_t)o * 64 + c0);
#pragma unroll
        for (int j = 0; j < 4; ++j) {
            float4 v = *(const float4*)&lacc[row * LROW + c0 + j * 4];
            dst[j] = v;
            float sv = (v.x + v.y) + (v.z + v.w);
            float qv = (v.x*v.x + v.y*v.y) + (v.z*v.z + v.w*v.w);
            if (j < 2) { s0 += sv; q0 += qv; } else { s1 += sv; q1 += qv; }
        }
    }
#pragma unroll
    for (int m = 4; m <= 32; m <<= 1) {
        s0 += __shfl_xor(s0, m); q0 += __shfl_xor(q0, m);
        s1 += __shfl_xor(s1, m); q1 += __shfl_xor(q1, m);
    }
    if (lane < 4) {
        int g = lane * 2;   // this lane's first group (cols g*8..)
        unsafeAtomicAdd(&stats[g],         s0);
        unsafeAtomicAdd(&stats[8 + g],     q0);
        unsafeAtomicAdd(&stats[g + 1],     s1);
        unsafeAtomicAdd(&stats[8 + g + 1], q1);
    }
}

// ===========================================================================
// GroupNorm apply (+residual, +leaky); fp32 and/or bf16 outputs.
// ===========================================================================
__global__ __launch_bounds__(256) void gn_apply_kernel(
    const float4* __restrict__ x, const float* __restrict__ stats,
    const float* __restrict__ gamma, const float* __restrict__ beta,
    const float4* resid, float4* out_f, bf16x4* out_bf,
    long total4, float invc, int do_leaky)
{
    __shared__ float sc[64], sh[64];
    if (threadIdx.x < 64) {
        int c = threadIdx.x, g = c >> 3;
        float mean = stats[g] * invc;
        float var  = fmaf(-mean, mean, stats[8 + g] * invc);
        float s    = rsqrtf(var + GN_EPS) * gamma[c];
        sc[c] = s;
        sh[c] = fmaf(-mean, s, beta[c]);
    }
    __syncthreads();
    const long stride = (long)gridDim.x * blockDim.x;
    for (long i = (long)blockIdx.x * blockDim.x + threadIdx.x; i < total4; i += stride) {
        float4 v = x[i];
        int c0 = ((int)(i & 15)) << 2;
        float4 r;
        r.x = fmaf(v.x, sc[c0 + 0], sh[c0 + 0]);
        r.y = fmaf(v.y, sc[c0 + 1], sh[c0 + 1]);
        r.z = fmaf(v.z, sc[c0 + 2], sh[c0 + 2]);
        r.w = fmaf(v.w, sc[c0 + 3], sh[c0 + 3]);
        if (resid) {
            float4 h4 = resid[i];
            r.x += h4.x; r.y += h4.y; r.z += h4.z; r.w += h4.w;
        }
        if (do_leaky) {
            r.x = r.x >= 0.f ? r.x : NEG_SLOPE * r.x;
            r.y = r.y >= 0.f ? r.y : NEG_SLOPE * r.y;
            r.z = r.z >= 0.f ? r.z : NEG_SLOPE * r.z;
            r.w = r.w >= 0.f ? r.w : NEG_SLOPE * r.w;
        }
        if (out_f) out_f[i] = r;
        if (out_bf) {
            bf16x4 o;
            o.x = (__bf16)r.x; o.y = (__bf16)r.y; o.z = (__bf16)r.z; o.w = (__bf16)r.w;
            out_bf[i] = o;
        }
    }
}

// ===========================================================================
// Legacy fallback kernels (used only if ws_size is insufficient)
// ===========================================================================
__global__ __launch_bounds__(256) void conv_kernel(
    const float* __restrict__ feats, const float* __restrict__ W,
    const int* __restrict__ in_map, const int* __restrict__ out_map,
    float* __restrict__ out, int M, int BPK)
{
    const int lane = threadIdx.x & 63;
    const int wv   = threadIdx.x >> 6;
    const int k    = blockIdx.x / BPK;
    const int blk  = blockIdx.x % BPK;
    const float* Wk = W + (size_t)k * 4096;
    float w[64];
#pragma unroll
    for (int c = 0; c < 64; ++c) w[c] = Wk[c * 64 + lane];
    __shared__ float fbuf[4][64];
    const int* im = in_map + (size_t)k * M;
    const int* om = out_map + (size_t)k * M;
    const int stride = BPK * 4;
    for (int m = blk * 4 + wv; m < M; m += stride) {
        int ii = im[m];
        int oi = om[m];
        float f = feats[(size_t)ii * 64 + lane];
        fbuf[wv][lane] = f;
        const float* fb = fbuf[wv];
        float a0 = 0.f, a1 = 0.f, a2 = 0.f, a3 = 0.f;
#pragma unroll
        for (int c = 0; c < 64; c += 4) {
            float4 f4 = *(const float4*)(fb + c);
            a0 = fmaf(f4.x, w[c + 0], a0);
            a1 = fmaf(f4.y, w[c + 1], a1);
            a2 = fmaf(f4.z, w[c + 2], a2);
            a3 = fmaf(f4.w, w[c + 3], a3);
        }
        unsafeAtomicAdd(out + (size_t)oi * 64 + lane, (a0 + a1) + (a2 + a3));
    }
}

__global__ __launch_bounds__(256) void gn_stats_kernel(
    const float4* __restrict__ x, float* __restrict__ stats, long total4)
{
    const int lane = threadIdx.x & 63;
    float s = 0.f, q = 0.f;
    const long stride = (long)gridDim.x * blockDim.x;
    for (long i = (long)blockIdx.x * blockDim.x + threadIdx.x; i < total4; i += stride) {
        float4 v = x[i];
        s += (v.x + v.y) + (v.z + v.w);
        q += (v.x * v.x + v.y * v.y) + (v.z * v.z + v.w * v.w);
    }
    s += __shfl_xor(s, 1);  q += __shfl_xor(q, 1);
    s += __shfl_xor(s, 16); q += __shfl_xor(q, 16);
    s += __shfl_xor(s, 32); q += __shfl_xor(q, 32);
    __shared__ float ls[4][16];
    const int wv = threadIdx.x >> 6;
    const int g = (lane >> 1) & 7;
    if (lane < 16 && (lane & 1) == 0) { ls[wv][g] = s; ls[wv][8 + g] = q; }
    __syncthreads();
    if (threadIdx.x < 16) {
        float t = (ls[0][threadIdx.x] + ls[1][threadIdx.x]) +
                  (ls[2][threadIdx.x] + ls[3][threadIdx.x]);
        unsafeAtomicAdd(stats + threadIdx.x, t);
    }
}

// ===========================================================================
extern "C" void kernel_launch(void* const* d_in, const int* in_sizes, int n_in,
                              void* d_out, int out_size, void* d_ws, size_t ws_size,
                              hipStream_t stream) {
    const float* x   = (const float*)d_in[0];
    const float* W1  = (const float*)d_in[1];
    const float* g1  = (const float*)d_in[2];
    const float* b1  = (const float*)d_in[3];
    const float* Wa1 = (const float*)d_in[4];
    const float* ga1 = (const float*)d_in[5];
    const float* ba1 = (const float*)d_in[6];
    const float* Wb1 = (const float*)d_in[7];
    const float* gb1 = (const float*)d_in[8];
    const float* bb1 = (const float*)d_in[9];
    const float* Wa2 = (const float*)d_in[10];
    const float* ga2 = (const float*)d_in[11];
    const float* ba2 = (const float*)d_in[12];
    const float* Wb2 = (const float*)d_in[13];
    const float* gb2 = (const float*)d_in[14];
    const float* bb2 = (const float*)d_in[15];
    const int* m1_in  = (const int*)d_in[16];
    const int* m1_out = (const int*)d_in[17];
    const int* m2_in  = (const int*)d_in[18];
    const int* m2_out = (const int*)d_in[19];

    const int N    = out_size / 64;
    const int M1   = in_sizes[16] / 8;
    const int M2   = in_sizes[18] / 27;
    const int E1   = 8 * M1;
    const int E2   = 27 * M2;
    const int tiles = (N + 63) / 64;
    const int NB1  = tiles * 8;
    const int NB2  = tiles * 27;

    float* h = (float*)d_out;
    const long  total4 = (long)N * 16;
    const float invc   = 1.f / ((float)N * 8.f);

    // ---- workspace layout (256B aligned) ----
    char* wp = (char*)d_ws;
    size_t off = 0;
    auto alloc = [&](size_t bytes) {
        void* p = wp + off;
        off = (off + bytes + 255) & ~(size_t)255;
        return p;
    };
    float*  acc   = (float*)alloc((size_t)N * 64 * 4);
    __bf16* hbf   = (__bf16*)alloc((size_t)N * 64 * 2);
    __bf16* ybf   = (__bf16*)alloc((size_t)N * 64 * 2);
    __bf16* Wfrag = (__bf16*)alloc((size_t)27 * 512 * 8 * 2);
    int*    base1 = (int*)alloc((size_t)(NB1 + 1) * 4);
    int*    base2 = (int*)alloc((size_t)(NB2 + 1) * 4);
    int*    cnt   = (int*)alloc((size_t)NB2 * 4);
    int*    part  = (int*)alloc(4096);
    int*    pk1   = (int*)alloc((size_t)(E1 + 16) * 4);
    int*    pk2   = (int*)alloc((size_t)(E2 + 16) * 4);
    float*  stats = (float*)alloc(64);
    const size_t need = off;

    if (ws_size < need) {
        // -------- legacy atomic fallback --------
        float* fy = acc + (size_t)N * 64;          // overlays hbf/ybf region
        float* st = fy + (size_t)N * 64;
        const size_t nbytes = (size_t)N * 64 * 4;
        auto convL = [&](const float* feats, const float* W, const int* im,
                         const int* om, int K, int M, int BPK) {
            hipMemsetAsync(acc, 0, nbytes, stream);
            conv_kernel<<<dim3(K * BPK), 256, 0, stream>>>(feats, W, im, om, acc, M, BPK);
        };
        auto gnL = [&](const float* gamma, const float* beta, const float* resid,
                       float* outp, int leaky) {
            hipMemsetAsync(st, 0, 16 * sizeof(float), stream);
            gn_stats_kernel<<<1024, 256, 0, stream>>>((const float4*)acc, st, total4);
            gn_apply_kernel<<<1024, 256, 0, stream>>>((const float4*)acc, st, gamma, beta,
                                                      (const float4*)resid, (float4*)outp,
                                                      nullptr, total4, invc, leaky);
        };
        convL(x, W1, m1_in, m1_out, 8, M1, 320); gnL(g1, b1, nullptr, h, 1);
        convL(h, Wa1, m2_in, m2_out, 27, M2, 96); gnL(ga1, ba1, nullptr, fy, 0);
        convL(fy, Wb1, m2_in, m2_out, 27, M2, 96); gnL(gb1, bb1, h, h, 1);
        convL(h, Wa2, m2_in, m2_out, 27, M2, 96); gnL(ga2, ba2, nullptr, fy, 0);
        convL(fy, Wb2, m2_in, m2_out, 27, M2, 96); gnL(gb2, bb2, h, h, 1);
        return;
    }

    // -------- fused implicit-GEMM path --------
    auto buildBinned = [&](const int* om, const int* im, int M, int TK, int NB,
                           int* base, int* pkArr) {
        const int BPK = 48;
        hipMemsetAsync(cnt, 0, (size_t)NB * 4, stream);
        hist_binned_kernel<<<dim3(TK * BPK), 256, 0, stream>>>(om, cnt, M, TK, BPK);
        const int nb = (NB + 1023) / 1024;
        scan1_kernel<<<nb, 256, 0, stream>>>(cnt, part, NB);
        scan2_kernel<<<1, 64, 0, stream>>>(part, nb);
        scan3_kernel<<<nb, 256, 0, stream>>>(cnt, part, base, NB);
        hipMemsetAsync(cnt, 0, (size_t)NB * 4, stream);
        scatter_binned_kernel<<<dim3(TK * BPK), 256, 0, stream>>>(om, im, base, cnt,
                                                                  pkArr, M, TK, BPK);
    };
    buildBinned(m1_out, m1_in, M1, 8, NB1, base1, pk1);
    buildBinned(m2_out, m2_in, M2, 27, NB2, base2, pk2);

    auto convF = [&](const void* feats, int f32in, const float* W, int TK,
                     const int* base, const int* pkArr) {
        wfrag_kernel<<<(TK * 512 + 255) / 256, 256, 0, stream>>>(W, Wfrag, TK);
        hipMemsetAsync(stats, 0, 64, stream);
        if (f32in)
            conv_fused_kernel<1><<<tiles, 256, 0, stream>>>(feats, Wfrag, base, pkArr,
                                                            acc, stats, N, TK);
        else
            conv_fused_kernel<0><<<tiles, 256, 0, stream>>>(feats, Wfrag, base, pkArr,
                                                            acc, stats, N, TK);
    };
    auto gn = [&](const float* gamma, const float* beta, const float* resid,
                  float* outf, __bf16* outbf, int leaky) {
        gn_apply_kernel<<<1024, 256, 0, stream>>>((const float4*)acc, stats, gamma, beta,
                                                  (const float4*)resid, (float4*)outf,
                                                  (bf16x4*)outbf, total4, invc, leaky);
    };

    // BasicConvolutionBlock (gathers fp32 x directly)
    convF(x, 1, W1, 8, base1, pk1);
    gn(g1, b1, nullptr, h, hbf, 1);
    // ResidualBlock 1
    convF(hbf, 0, Wa1, 27, base2, pk2);
    gn(ga1, ba1, nullptr, nullptr, ybf, 0);
    convF(ybf, 0, Wb1, 27, base2, pk2);
    gn(gb1, bb1, h, h, hbf, 1);
    // ResidualBlock 2
    convF(hbf, 0, Wa2, 27, base2, pk2);
    gn(ga2, ba2, nullptr, nullptr, ybf, 0);
    convF(ybf, 0, Wb2, 27, base2, pk2);
    gn(gb2, bb2, h, h, hbf, 1);
}

// Round 7
// 1172.544 us; speedup vs baseline: 3.0844x; 3.0844x over previous
//
#include <hip/hip_runtime.h>

#define NEG_SLOPE 0.01f
#define GN_EPS 1e-5f

typedef __attribute__((ext_vector_type(8))) __bf16 bf16x8;
typedef __attribute__((ext_vector_type(4))) __bf16 bf16x4;
typedef __attribute__((ext_vector_type(4))) float f32x4;

__device__ __forceinline__ float bf_lo(unsigned v) { return __uint_as_float(v << 16); }
__device__ __forceinline__ float bf_hi(unsigned v) { return __uint_as_float(v & 0xffff0000u); }

// ===========================================================================
// CSR build: histogram -> 2-level exclusive scan -> inverse-permutation scatter
// ===========================================================================
__global__ __launch_bounds__(256) void hist_kernel(
    const int* __restrict__ om, int* __restrict__ cnt, int E)
{
    const int stride = gridDim.x * blockDim.x;
    for (int e = blockIdx.x * blockDim.x + threadIdx.x; e < E; e += stride)
        atomicAdd(&cnt[om[e]], 1);
}

__global__ __launch_bounds__(256) void scan1_kernel(
    const int* __restrict__ cnt, int* __restrict__ part, int N)
{
    __shared__ int ls[256];
    int b = blockIdx.x, t = threadIdx.x;
    int i0 = b * 1024 + t * 4, s = 0;
#pragma unroll
    for (int u = 0; u < 4; ++u) if (i0 + u < N) s += cnt[i0 + u];
    ls[t] = s; __syncthreads();
    for (int off = 128; off > 0; off >>= 1) {
        if (t < off) ls[t] += ls[t + off];
        __syncthreads();
    }
    if (t == 0) part[b] = ls[0];
}

__global__ void scan2_kernel(int* __restrict__ part, int nb)
{
    if (blockIdx.x == 0 && threadIdx.x == 0) {
        int run = 0;
        for (int i = 0; i < nb; ++i) { int v = part[i]; part[i] = run; run += v; }
    }
}

__global__ __launch_bounds__(256) void scan3_kernel(
    const int* __restrict__ cnt, const int* __restrict__ part,
    int* __restrict__ base, int N)
{
    __shared__ int ls[256];
    int b = blockIdx.x, t = threadIdx.x;
    int i0 = b * 1024 + t * 4;
    int v0 = 0, v1 = 0, v2 = 0, v3 = 0;
    if (i0 + 0 < N) v0 = cnt[i0 + 0];
    if (i0 + 1 < N) v1 = cnt[i0 + 1];
    if (i0 + 2 < N) v2 = cnt[i0 + 2];
    if (i0 + 3 < N) v3 = cnt[i0 + 3];
    int s = v0 + v1 + v2 + v3;
    ls[t] = s; __syncthreads();
    for (int off = 1; off < 256; off <<= 1) {
        int x = (t >= off) ? ls[t - off] : 0;
        __syncthreads();
        ls[t] += x;
        __syncthreads();
    }
    int run = part[b] + ls[t] - s;   // exclusive prefix
    if (i0 + 0 < N) { base[i0 + 0] = run; run += v0; if (i0 + 0 == N - 1) base[N] = run; }
    if (i0 + 1 < N) { base[i0 + 1] = run; run += v1; if (i0 + 1 == N - 1) base[N] = run; }
    if (i0 + 2 < N) { base[i0 + 2] = run; run += v2; if (i0 + 2 == N - 1) base[N] = run; }
    if (i0 + 3 < N) { base[i0 + 3] = run; run += v3; if (i0 + 3 == N - 1) base[N] = run; }
}

__global__ __launch_bounds__(256) void scatter_kernel(
    const int* __restrict__ om, const int* __restrict__ base,
    int* __restrict__ cur, int* __restrict__ inv, int E)
{
    const int stride = gridDim.x * blockDim.x;
    for (int e = blockIdx.x * blockDim.x + threadIdx.x; e < E; e += stride) {
        int o = om[e];
        int p = base[o] + atomicAdd(&cur[o], 1);
        inv[e] = p;           // edge e's row lands at sorted position p
    }
}

// ===========================================================================
// Phase A: per-offset GEMM via bf16 MFMA; C row for edge e written to
// sorted position inv[e] (so Phase B streams contiguously). Stores are
// NON-TEMPORAL: C is written once, read once by reduce -> no-allocate hint
// kills the L2 write-allocate fills (round-3 FETCH 99MB vs 19MB source).
// A layout (16x16x32): lane holds A[m=l&15][c=(l>>4)*8+j]; B: B[c][n=l&15];
// D: row=(l>>4)*4+r, col=l&15.
// ===========================================================================
template<int F32IN>
__global__ __launch_bounds__(256) void conv_mfma_kernel(
    const void* __restrict__ feats, const float* __restrict__ W,
    const int* __restrict__ in_map, const int* __restrict__ inv,
    __bf16* __restrict__ C, int M, int BPK)
{
    const int lane = threadIdx.x & 63;
    const int wv   = threadIdx.x >> 6;
    const int k    = blockIdx.x / BPK;
    const int blk  = blockIdx.x % BPK;
    const int l15  = lane & 15;
    const int lg   = lane >> 4;         // 0..3

    // B fragments: b[nt][h] covers cols nt*16+l15, K-half h
    const float* Wk = W + (size_t)k * 4096;
    bf16x8 b[4][2];
#pragma unroll
    for (int nt = 0; nt < 4; ++nt)
#pragma unroll
        for (int h = 0; h < 2; ++h)
#pragma unroll
            for (int j = 0; j < 8; ++j)
                b[nt][h][j] = (__bf16)Wk[(h * 32 + lg * 8 + j) * 64 + nt * 16 + l15];

    const int* imk   = in_map + (size_t)k * M;
    const int ntiles = (M + 15) >> 4;
    const int wpk    = BPK * 4;

    for (int t = blk * 4 + wv; t < ntiles; t += wpk) {
        int m  = t * 16 + l15;
        int mc = m < M ? m : M - 1;
        int ii = imk[mc];
        bf16x8 a0, a1;
        if (F32IN) {
            const float4* rp = (const float4*)((const float*)feats + (size_t)ii * 64 + lg * 8);
            float4 u0 = rp[0], u1 = rp[1];
            float4 u2 = rp[8], u3 = rp[9];   // +32 channels
            a0[0] = (__bf16)u0.x; a0[1] = (__bf16)u0.y; a0[2] = (__bf16)u0.z; a0[3] = (__bf16)u0.w;
            a0[4] = (__bf16)u1.x; a0[5] = (__bf16)u1.y; a0[6] = (__bf16)u1.z; a0[7] = (__bf16)u1.w;
            a1[0] = (__bf16)u2.x; a1[1] = (__bf16)u2.y; a1[2] = (__bf16)u2.z; a1[3] = (__bf16)u2.w;
            a1[4] = (__bf16)u3.x; a1[5] = (__bf16)u3.y; a1[6] = (__bf16)u3.z; a1[7] = (__bf16)u3.w;
        } else {
            const bf16x8* rp = (const bf16x8*)((const __bf16*)feats + (size_t)ii * 64 + lg * 8);
            a0 = rp[0];
            a1 = rp[4];   // +32 channels
        }
        f32x4 c0 = {0.f,0.f,0.f,0.f}, c1 = c0, c2 = c0, c3 = c0;
        c0 = __builtin_amdgcn_mfma_f32_16x16x32_bf16(a0, b[0][0], c0, 0, 0, 0);
        c1 = __builtin_amdgcn_mfma_f32_16x16x32_bf16(a0, b[1][0], c1, 0, 0, 0);
        c2 = __builtin_amdgcn_mfma_f32_16x16x32_bf16(a0, b[2][0], c2, 0, 0, 0);
        c3 = __builtin_amdgcn_mfma_f32_16x16x32_bf16(a0, b[3][0], c3, 0, 0, 0);
        c0 = __builtin_amdgcn_mfma_f32_16x16x32_bf16(a1, b[0][1], c0, 0, 0, 0);
        c1 = __builtin_amdgcn_mfma_f32_16x16x32_bf16(a1, b[1][1], c1, 0, 0, 0);
        c2 = __builtin_amdgcn_mfma_f32_16x16x32_bf16(a1, b[2][1], c2, 0, 0, 0);
        c3 = __builtin_amdgcn_mfma_f32_16x16x32_bf16(a1, b[3][1], c3, 0, 0, 0);

        const int e_base = k * M + t * 16;
        f32x4 cc[4] = {c0, c1, c2, c3};
#pragma unroll
        for (int r = 0; r < 4; ++r) {
            int row = lg * 4 + r;
            if (t * 16 + row < M) {
                int p = inv[e_base + row];            // broadcast within l15-group
                __bf16* cr = C + (size_t)p * 64 + l15;
#pragma unroll
                for (int nt = 0; nt < 4; ++nt) {
                    __bf16 v = (__bf16)cc[nt][r];
                    __builtin_nontemporal_store(v, cr + nt * 16);
                }
            }
        }
    }
}

// ===========================================================================
// Phase B: segmented streaming reduce + FUSED GroupNorm stats. Grid-stride:
// 2048 blocks x 4 waves, one wave per output row per iter; C rows for output
// o are contiguous [base[o], base[o+1]). 2 rows/iter: lane = (row parity)<<5
// | channel-pair, uint nt-load = 2 bf16. Per-wave stat registers -> block
// LDS combine -> 16 global atomics per block.
// ===========================================================================
__global__ __launch_bounds__(256) void reduce_kernel(
    const unsigned short* __restrict__ C, const int* __restrict__ base,
    float* __restrict__ out, float* __restrict__ stats, int N)
{
    const int lane = threadIdx.x & 63;
    const int wv   = threadIdx.x >> 6;
    const int c2   = lane & 31;       // channel pair index (channels 2c2, 2c2+1)
    const int half = lane >> 5;       // row parity
    float rs = 0.f, rq = 0.f;

    const int ostride = gridDim.x * 4;
    for (int o = blockIdx.x * 4 + wv; o < N; o += ostride) {
        const int s = base[o], t = base[o + 1];
        float s0 = 0.f, s1 = 0.f;
        for (int i = s + half; i < t; i += 2) {
            unsigned v = __builtin_nontemporal_load(
                (const unsigned*)(C + (size_t)i * 64 + c2 * 2));
            s0 += bf_lo(v);
            s1 += bf_hi(v);
        }
        s0 += __shfl_xor(s0, 32);
        s1 += __shfl_xor(s1, 32);
        if (half == 0) {
            float2 r = {s0, s1};
            *(float2*)(out + (size_t)o * 64 + c2 * 2) = r;
            rs += s0 + s1;                    // both channels in group c2>>2
            rq += s0 * s0 + s1 * s1;
        }
    }
    // combine lanes of the same group g = c2>>2 (xor 1,2 stays within half)
    rs += __shfl_xor(rs, 1); rq += __shfl_xor(rq, 1);
    rs += __shfl_xor(rs, 2); rq += __shfl_xor(rq, 2);
    __shared__ float ls[4][16];
    const int g = c2 >> 2;
    if (half == 0 && (c2 & 3) == 0) { ls[wv][g] = rs; ls[wv][8 + g] = rq; }
    __syncthreads();
    if (threadIdx.x < 16) {
        float t = (ls[0][threadIdx.x] + ls[1][threadIdx.x]) +
                  (ls[2][threadIdx.x] + ls[3][threadIdx.x]);
        unsafeAtomicAdd(stats + threadIdx.x, t);
    }
}

// ===========================================================================
// Legacy atomic-scatter conv + standalone gn_stats (ws_size fallback path)
// ===========================================================================
__global__ __launch_bounds__(256) void conv_kernel(
    const float* __restrict__ feats, const float* __restrict__ W,
    const int* __restrict__ in_map, const int* __restrict__ out_map,
    float* __restrict__ out, int M, int BPK)
{
    const int lane = threadIdx.x & 63;
    const int wv   = threadIdx.x >> 6;
    const int k    = blockIdx.x / BPK;
    const int blk  = blockIdx.x % BPK;
    const float* Wk = W + (size_t)k * 4096;
    float w[64];
#pragma unroll
    for (int c = 0; c < 64; ++c) w[c] = Wk[c * 64 + lane];
    __shared__ float fbuf[4][64];
    const int* im = in_map + (size_t)k * M;
    const int* om = out_map + (size_t)k * M;
    const int stride = BPK * 4;
    for (int m = blk * 4 + wv; m < M; m += stride) {
        int ii = im[m];
        int oi = om[m];
        float f = feats[(size_t)ii * 64 + lane];
        fbuf[wv][lane] = f;
        const float* fb = fbuf[wv];
        float a0 = 0.f, a1 = 0.f, a2 = 0.f, a3 = 0.f;
#pragma unroll
        for (int c = 0; c < 64; c += 4) {
            float4 f4 = *(const float4*)(fb + c);
            a0 = fmaf(f4.x, w[c + 0], a0);
            a1 = fmaf(f4.y, w[c + 1], a1);
            a2 = fmaf(f4.z, w[c + 2], a2);
            a3 = fmaf(f4.w, w[c + 3], a3);
        }
        unsafeAtomicAdd(out + (size_t)oi * 64 + lane, (a0 + a1) + (a2 + a3));
    }
}

__global__ __launch_bounds__(256) void gn_stats_kernel(
    const float4* __restrict__ x, float* __restrict__ stats, long total4)
{
    const int lane = threadIdx.x & 63;
    float s = 0.f, q = 0.f;
    const long stride = (long)gridDim.x * blockDim.x;
    for (long i = (long)blockIdx.x * blockDim.x + threadIdx.x; i < total4; i += stride) {
        float4 v = x[i];
        s += (v.x + v.y) + (v.z + v.w);
        q += (v.x * v.x + v.y * v.y) + (v.z * v.z + v.w * v.w);
    }
    s += __shfl_xor(s, 1);  q += __shfl_xor(q, 1);
    s += __shfl_xor(s, 16); q += __shfl_xor(q, 16);
    s += __shfl_xor(s, 32); q += __shfl_xor(q, 32);
    __shared__ float ls[4][16];
    const int wv = threadIdx.x >> 6;
    const int g = (lane >> 1) & 7;
    if (lane < 16 && (lane & 1) == 0) { ls[wv][g] = s; ls[wv][8 + g] = q; }
    __syncthreads();
    if (threadIdx.x < 16) {
        float t = (ls[0][threadIdx.x] + ls[1][threadIdx.x]) +
                  (ls[2][threadIdx.x] + ls[3][threadIdx.x]);
        unsafeAtomicAdd(stats + threadIdx.x, t);
    }
}

// ===========================================================================
// GroupNorm apply (+residual, +leaky); fp32 and/or bf16 outputs.
// ===========================================================================
__global__ __launch_bounds__(256) void gn_apply_kernel(
    const float4* __restrict__ x, const float* __restrict__ stats,
    const float* __restrict__ gamma, const float* __restrict__ beta,
    const float4* resid, float4* out_f, bf16x4* out_bf,
    long total4, float invc, int do_leaky)
{
    __shared__ float sc[64], sh[64];
    if (threadIdx.x < 64) {
        int c = threadIdx.x, g = c >> 3;
        float mean = stats[g] * invc;
        float var  = fmaf(-mean, mean, stats[8 + g] * invc);
        float s    = rsqrtf(var + GN_EPS) * gamma[c];
        sc[c] = s;
        sh[c] = fmaf(-mean, s, beta[c]);
    }
    __syncthreads();
    const long stride = (long)gridDim.x * blockDim.x;
    for (long i = (long)blockIdx.x * blockDim.x + threadIdx.x; i < total4; i += stride) {
        float4 v = x[i];
        int c0 = ((int)(i & 15)) << 2;
        float4 r;
        r.x = fmaf(v.x, sc[c0 + 0], sh[c0 + 0]);
        r.y = fmaf(v.y, sc[c0 + 1], sh[c0 + 1]);
        r.z = fmaf(v.z, sc[c0 + 2], sh[c0 + 2]);
        r.w = fmaf(v.w, sc[c0 + 3], sh[c0 + 3]);
        if (resid) {
            float4 h4 = resid[i];
            r.x += h4.x; r.y += h4.y; r.z += h4.z; r.w += h4.w;
        }
        if (do_leaky) {
            r.x = r.x >= 0.f ? r.x : NEG_SLOPE * r.x;
            r.y = r.y >= 0.f ? r.y : NEG_SLOPE * r.y;
            r.z = r.z >= 0.f ? r.z : NEG_SLOPE * r.z;
            r.w = r.w >= 0.f ? r.w : NEG_SLOPE * r.w;
        }
        if (out_f) out_f[i] = r;
        if (out_bf) {
            bf16x4 o;
            o.x = (__bf16)r.x; o.y = (__bf16)r.y; o.z = (__bf16)r.z; o.w = (__bf16)r.w;
            out_bf[i] = o;
        }
    }
}

// ===========================================================================
extern "C" void kernel_launch(void* const* d_in, const int* in_sizes, int n_in,
                              void* d_out, int out_size, void* d_ws, size_t ws_size,
                              hipStream_t stream) {
    const float* x   = (const float*)d_in[0];
    const float* W1  = (const float*)d_in[1];
    const float* g1  = (const float*)d_in[2];
    const float* b1  = (const float*)d_in[3];
    const float* Wa1 = (const float*)d_in[4];
    const float* ga1 = (const float*)d_in[5];
    const float* ba1 = (const float*)d_in[6];
    const float* Wb1 = (const float*)d_in[7];
    const float* gb1 = (const float*)d_in[8];
    const float* bb1 = (const float*)d_in[9];
    const float* Wa2 = (const float*)d_in[10];
    const float* ga2 = (const float*)d_in[11];
    const float* ba2 = (const float*)d_in[12];
    const float* Wb2 = (const float*)d_in[13];
    const float* gb2 = (const float*)d_in[14];
    const float* bb2 = (const float*)d_in[15];
    const int* m1_in  = (const int*)d_in[16];
    const int* m1_out = (const int*)d_in[17];
    const int* m2_in  = (const int*)d_in[18];
    const int* m2_out = (const int*)d_in[19];

    const int N   = out_size / 64;
    const int M1  = in_sizes[16] / 8;
    const int M2  = in_sizes[18] / 27;
    const int E1  = 8 * M1;
    const int E2  = 27 * M2;
    const int Emax = E1 > E2 ? E1 : E2;

    float* h = (float*)d_out;
    const long  total4 = (long)N * 16;
    const float invc   = 1.f / ((float)N * 8.f);

    // ---- workspace layout (256B aligned) ----
    char* wp = (char*)d_ws;
    size_t off = 0;
    auto alloc = [&](size_t bytes) {
        void* p = wp + off;
        off = (off + bytes + 255) & ~(size_t)255;
        return p;
    };
    float*  acc   = (float*)alloc((size_t)N * 64 * 4);
    __bf16* hbf   = (__bf16*)alloc((size_t)N * 64 * 2);
    __bf16* ybf   = (__bf16*)alloc((size_t)N * 64 * 2);
    __bf16* Cbuf  = (__bf16*)alloc((size_t)Emax * 64 * 2);
    int*    base1 = (int*)alloc((size_t)(N + 1) * 4);
    int*    base2 = (int*)alloc((size_t)(N + 1) * 4);
    int*    cnt   = (int*)alloc((size_t)N * 4);
    int*    part  = (int*)alloc(4096);
    int*    inv1  = (int*)alloc((size_t)E1 * 4);
    int*    inv2  = (int*)alloc((size_t)E2 * 4);
    float*  stats = (float*)alloc(64);
    const size_t need = off;

    if (ws_size < need) {
        // -------- legacy atomic fallback --------
        float* y  = acc + (size_t)N * 64;
        float* st = y + (size_t)N * 64;
        const size_t nbytes = (size_t)N * 64 * 4;
        auto convL = [&](const float* feats, const float* W, const int* im,
                         const int* om, int K, int M, int BPK) {
            hipMemsetAsync(acc, 0, nbytes, stream);
            conv_kernel<<<dim3(K * BPK), 256, 0, stream>>>(feats, W, im, om, acc, M, BPK);
        };
        auto gnL = [&](const float* gamma, const float* beta, const float* resid,
                       float* outp, int leaky) {
            hipMemsetAsync(st, 0, 16 * sizeof(float), stream);
            gn_stats_kernel<<<1024, 256, 0, stream>>>((const float4*)acc, st, total4);
            gn_apply_kernel<<<1024, 256, 0, stream>>>((const float4*)acc, st, gamma, beta,
                                                      (const float4*)resid, (float4*)outp,
                                                      nullptr, total4, invc, leaky);
        };
        convL(x, W1, m1_in, m1_out, 8, M1, 320); gnL(g1, b1, nullptr, h, 1);
        convL(h, Wa1, m2_in, m2_out, 27, M2, 96); gnL(ga1, ba1, nullptr, y, 0);
        convL(y, Wb1, m2_in, m2_out, 27, M2, 96); gnL(gb1, bb1, h, h, 1);
        convL(h, Wa2, m2_in, m2_out, 27, M2, 96); gnL(ga2, ba2, nullptr, y, 0);
        convL(y, Wb2, m2_in, m2_out, 27, M2, 96); gnL(gb2, bb2, h, h, 1);
        return;
    }

    // -------- MFMA + sorted-streaming-reduce path (round-3 proven) --------
    const int nb = (N + 1023) / 1024;
    auto buildCSR = [&](const int* om, int E, int* base, int* inv) {
        hipMemsetAsync(cnt, 0, (size_t)N * 4, stream);
        hist_kernel<<<2048, 256, 0, stream>>>(om, cnt, E);
        scan1_kernel<<<nb, 256, 0, stream>>>(cnt, part, N);
        scan2_kernel<<<1, 64, 0, stream>>>(part, nb);
        scan3_kernel<<<nb, 256, 0, stream>>>(cnt, part, base, N);
        hipMemsetAsync(cnt, 0, (size_t)N * 4, stream);
        scatter_kernel<<<2048, 256, 0, stream>>>(om, base, cnt, inv, E);
    };
    buildCSR(m1_out, E1, base1, inv1);
    buildCSR(m2_out, E2, base2, inv2);

    auto conv = [&](const void* feats, int f32in, const float* W, const int* im,
                    int K, int M, int BPK, const int* base, const int* inv) {
        hipMemsetAsync(stats, 0, 64, stream);
        if (f32in)
            conv_mfma_kernel<1><<<dim3(K * BPK), 256, 0, stream>>>(feats, W, im, inv, Cbuf, M, BPK);
        else
            conv_mfma_kernel<0><<<dim3(K * BPK), 256, 0, stream>>>(feats, W, im, inv, Cbuf, M, BPK);
        reduce_kernel<<<2048, 256, 0, stream>>>((const unsigned short*)Cbuf, base,
                                                acc, stats, N);
    };
    auto gn = [&](const float* gamma, const float* beta, const float* resid,
                  float* outf, __bf16* outbf, int leaky) {
        gn_apply_kernel<<<1024, 256, 0, stream>>>((const float4*)acc, stats, gamma, beta,
                                                  (const float4*)resid, (float4*)outf,
                                                  (bf16x4*)outbf, total4, invc, leaky);
    };

    // BasicConvolutionBlock (gathers fp32 x directly)
    conv(x, 1, W1, m1_in, 8, M1, 128, base1, inv1);
    gn(g1, b1, nullptr, h, hbf, 1);
    // ResidualBlock 1
    conv(hbf, 0, Wa1, m2_in, 27, M2, 64, base2, inv2);
    gn(ga1, ba1, nullptr, nullptr, ybf, 0);
    conv(ybf, 0, Wb1, m2_in, 27, M2, 64, base2, inv2);
    gn(gb1, bb1, h, h, hbf, 1);
    // ResidualBlock 2
    conv(hbf, 0, Wa2, m2_in, 27, M2, 64, base2, inv2);
    gn(ga2, ba2, nullptr, nullptr, ybf, 0);
    conv(ybf, 0, Wb2, m2_in, 27, M2, 64, base2, inv2);
    gn(gb2, bb2, h, h, hbf, 1);
}